// Round 5
// baseline (496.117 us; speedup 1.0000x reference)
//
#include <hip/hip_runtime.h>
#include <hip/hip_bf16.h>

// 12-qubit statevector pipeline, fp32.
// prep -> enc (512 x 1-wave blocks) -> proj (2064 x 1-wave blocks) -> head.
// LDS transposes: 64x65-padded plane, immediate offsets, 2-way banks (free).
// All circuit permutations folded into compile-time register/lane relabels.
// R5 fix: enc init tree now a plain product tree over PHYSICAL register bits
// (phys y = W(logical w) means the ladder factors g_k ARE the phys bits);
// launch_bounds (64,2) so the 128-VGPR state never spills.

// ---------------- ws layout (floats) ----------------
#define N_STATE_F (512 * 8192)
#define WS_FEAT   N_STATE_F               // K 12288 | V 12288 | Q 192
#define WS_PTAB   (WS_FEAT + 24768)       // 144 gates * 4
#define WS_UTAB   (WS_PTAB + 576)         // 36 gates * 8
#define WS_TOTAL  (WS_UTAB + 288)

#define WMAP(m) ((m) ^ (((m) << 1) & 63))   // W(x) = x ^ ((x<<1)&63)
#define ENC_PI 3.14159265358979323846f
#define ENC_RS2 0.70710678118654752440f

__device__ __forceinline__ float xorf(float a, unsigned m) {
  return __int_as_float(__float_as_int(a) ^ (int)m);
}

// ---------- gate bodies on register bits (64 amps/thread) ----------
// U3, u = {ct,0,u01r,u01i,u10r,u10i,u11r,u11i} (u00 real)
template <int B>
__device__ __forceinline__ void u3g(float (&ar)[64], float (&ai)[64], const float* u) {
  float u00 = u[0], u01r = u[2], u01i = u[3], u10r = u[4], u10i = u[5], u11r = u[6], u11i = u[7];
#pragma unroll
  for (int m = 0; m < 32; ++m) {
    const int p0 = ((m >> B) << (B + 1)) | (m & ((1 << B) - 1));
    const int p1 = p0 | (1 << B);
    float x0r = ar[p0], x0i = ai[p0], x1r = ar[p1], x1i = ai[p1];
    ar[p0] = u00 * x0r + u01r * x1r - u01i * x1i;
    ai[p0] = u00 * x0i + u01r * x1i + u01i * x1r;
    ar[p1] = u10r * x0r - u10i * x0i + u11r * x1r - u11i * x1i;
    ai[p1] = u10r * x0i + u10i * x0r + u11r * x1i + u11i * x1r;
  }
}
__device__ __forceinline__ void u3Group6(float (&ar)[64], float (&ai)[64], const float* ub) {
  u3g<0>(ar, ai, ub);       u3g<1>(ar, ai, ub + 8);   u3g<2>(ar, ai, ub + 16);
  u3g<3>(ar, ai, ub + 24);  u3g<4>(ar, ai, ub + 32);  u3g<5>(ar, ai, ub + 40);
}

// U3 on logical reg-bit B when registers are W-relabeled (phys y = W(logical w)).
// Pair partner: y ^ W(1<<B); 0-side: parity(y & ((2<<B)-1)) == 0.
template <int B>
__device__ __forceinline__ void u3gW(float (&ar)[64], float (&ai)[64], const float* u) {
  const int WB = (B == 5) ? 32 : (3 << B);
  const int MB = (2 << B) - 1;
  float u00 = u[0], u01r = u[2], u01i = u[3], u10r = u[4], u10i = u[5], u11r = u[6], u11i = u[7];
#pragma unroll
  for (int y = 0; y < 64; ++y) {
    if (__popc(y & MB) & 1) continue;
    const int p0 = y, p1 = y ^ WB;
    float x0r = ar[p0], x0i = ai[p0], x1r = ar[p1], x1i = ai[p1];
    ar[p0] = u00 * x0r + u01r * x1r - u01i * x1i;
    ai[p0] = u00 * x0i + u01r * x1i + u01i * x1r;
    ar[p1] = u10r * x0r - u10i * x0i + u11r * x1r - u11i * x1i;
    ai[p1] = u10r * x0i + u10i * x0r + u11r * x1i + u11i * x1r;
  }
}
__device__ __forceinline__ void u3Group6W(float (&ar)[64], float (&ai)[64], const float* ub) {
  u3gW<0>(ar, ai, ub);       u3gW<1>(ar, ai, ub + 8);   u3gW<2>(ar, ai, ub + 16);
  u3gW<3>(ar, ai, ub + 24);  u3gW<4>(ar, ai, ub + 32);  u3gW<5>(ar, ai, ub + 40);
}

// Fused RY+RZ (global phase dropped): G = diag(1, e^{i phi}) * RY(theta)
template <int B>
__device__ __forceinline__ void ryrzg(float (&ar)[64], float (&ai)[64], float4 g) {
  float c = g.x, s = g.y, zr = g.z, zi = g.w;
#pragma unroll
  for (int m = 0; m < 32; ++m) {
    const int p0 = ((m >> B) << (B + 1)) | (m & ((1 << B) - 1));
    const int p1 = p0 | (1 << B);
    float x0r = ar[p0], x0i = ai[p0], x1r = ar[p1], x1i = ai[p1];
    float n0r = c * x0r - s * x1r;
    float n0i = c * x0i - s * x1i;
    float wr  = s * x0r + c * x1r;
    float wi  = s * x0i + c * x1i;
    ar[p0] = n0r;               ai[p0] = n0i;
    ar[p1] = wr * zr - wi * zi; ai[p1] = wr * zi + wi * zr;
  }
}
__device__ __forceinline__ void ryrzGroup6(float (&ar)[64], float (&ai)[64], const float4* gt) {
  ryrzg<0>(ar, ai, gt[0]); ryrzg<1>(ar, ai, gt[1]); ryrzg<2>(ar, ai, gt[2]);
  ryrzg<3>(ar, ai, gt[3]); ryrzg<4>(ar, ai, gt[4]); ryrzg<5>(ar, ai, gt[5]);
}

// ---------- transposes: 64x65-padded single plane, immediate offsets ----------
// Layout A: lane L holds j=(L<<6)|r.  Layout B: lane l holds j=(r<<6)|l.

__device__ __forceinline__ void xpBtoA(float* M, int l, float (&v)[64]) {
  float* wp = M + l;                 // write M[65w + l]
  const float* rp = M + 65 * l;      // read  M[65l + r]
#pragma unroll
  for (int w = 0; w < 64; ++w) wp[65 * w] = v[w];
  __syncthreads();
#pragma unroll
  for (int r = 0; r < 64; ++r) v[r] = rp[r];
  __syncthreads();
}
// same but source registers are W-relabeled (enc first transpose)
__device__ __forceinline__ void xpBtoA_W(float* M, int l, float (&v)[64]) {
  float* wp = M + l;
  const float* rp = M + 65 * l;
#pragma unroll
  for (int w = 0; w < 64; ++w) wp[65 * w] = v[WMAP(w)];
  __syncthreads();
#pragma unroll
  for (int r = 0; r < 64; ++r) v[r] = rp[r];
  __syncthreads();
}
// A -> B with CX_LONG fold: read M[65*(w ^ (l0<<5)) + l]
__device__ __forceinline__ void xpAtoB_m2(float* M, int l, float (&v)[64]) {
  float* wp = M + 65 * l;
  const int off = (l & 1) ? 65 * 32 : 0;
  const float* rLo = M + l + off;
  const float* rHi = M + l - off;
#pragma unroll
  for (int r = 0; r < 64; ++r) wp[r] = v[r];
  __syncthreads();
#pragma unroll
  for (int w = 0; w < 32; ++w) v[w] = rLo[65 * w];
#pragma unroll
  for (int w = 32; w < 64; ++w) v[w] = rHi[65 * w];
  __syncthreads();
}
// A -> B with CX_LADDER fold (pre-swap applied outside, both planes):
// read M[65*W(w) + C(l)]
__device__ __forceinline__ void xpAtoB_map3(float* M, int l, float (&v)[64]) {
  float* wp = M + 65 * l;
  const float* rp = M + (l ^ ((l << 1) & 63));
#pragma unroll
  for (int r = 0; r < 64; ++r) wp[r] = v[r];
  __syncthreads();
#pragma unroll
  for (int w = 0; w < 64; ++w) v[w] = rp[65 * WMAP(w)];
  __syncthreads();
}

// ---------- CZ phases in layout A ----------
__device__ __forceinline__ void czA_555(float (&ar)[64], float (&ai)[64], int l) {
  unsigned laneM = (unsigned)(__popc((l & (l >> 1)) & 0x15) & 1) << 31;
#pragma unroll
  for (int r = 0; r < 64; ++r) {
    unsigned m = laneM ^ ((unsigned)(__popc((r & (r >> 1)) & 0x15) & 1) << 31);
    ar[r] = xorf(ar[r], m); ai[r] = xorf(ai[r], m);
  }
}
__device__ __forceinline__ void czA_2AA(float (&ar)[64], float (&ai)[64], int l) {
  unsigned laneM  = (unsigned)(__popc((l & (l >> 1)) & 0xA) & 1) << 31;
  unsigned laneM2 = laneM ^ ((unsigned)(l & 1) << 31);  // cross pair (5,6)=r5&l0
#pragma unroll
  for (int r = 0; r < 64; ++r) {
    unsigned sel = (r >= 32) ? laneM2 : laneM;
    unsigned m = sel ^ ((unsigned)(__popc((r & (r >> 1)) & 0xA) & 1) << 31);
    ar[r] = xorf(ar[r], m); ai[r] = xorf(ai[r], m);
  }
}

// ---------------- prep: gate tables -> ws ----------------
__global__ void prep_kernel(const float* __restrict__ hparams,
                            const float* __restrict__ resp, float* __restrict__ ws) {
  int t = threadIdx.x;
  float4* ptab = (float4*)(ws + WS_PTAB);
  for (int idx = t; idx < 144; idx += 256) {
    int pj = idx / 24, k = idx % 24;
    const float* hp = hparams + pj * 48;
    float s, c;  sincosf(0.5f * hp[2 * k], &s, &c);
    float zi, zr; sincosf(hp[2 * k + 1], &zi, &zr);
    ptab[idx] = make_float4(c, s, zr, zi);
  }
  if (t < 36) {
    const float* rp = resp + t * 3;
    float st, ct;  sincosf(0.5f * rp[0], &st, &ct);
    float sp2, cp; sincosf(rp[1], &sp2, &cp);
    float sl, cl;  sincosf(rp[2], &sl, &cl);
    float spl, cpl; sincosf(rp[1] + rp[2], &spl, &cpl);
    float* u = ws + WS_UTAB + t * 8;
    u[0] = ct;       u[1] = 0.0f;
    u[2] = -cl * st; u[3] = -sl * st;
    u[4] = cp * st;  u[5] = sp2 * st;
    u[6] = cpl * ct; u[7] = spl * ct;
  }
}

// ---------------- enc: one wave per state ----------------
__global__ __launch_bounds__(64, 2) void enc_kernel(
    const float* __restrict__ seq, const float* __restrict__ utabG,
    float* __restrict__ wsStates) {
  __shared__ float M[4160];
  const int l = threadIdx.x;
  const int s = blockIdx.x;
  const float x = seq[s];
  const int l5 = (l >> 5) & 1;

  // per-lane init-gate amplitudes: f_q(0)=(a0r,a0i), f_q(1)=(a1r,a1i)
  float a0r[12], a0i[12], a1r[12], a1i[12];
#pragma unroll
  for (int q = 0; q < 12; ++q) {
    float th = x * (ENC_PI * (float)(q + 1) / 12.0f);
    float ph = x * (ENC_PI / (float)(q + 1));
    float sn, cs;  sincosf(0.5f * th, &sn, &cs);
    float zi, zr;  sincosf(0.5f * ph, &zi, &zr);
    float k0 = (cs - sn) * ENC_RS2, k1 = (cs + sn) * ENC_RS2;
    a0r[q] = k0 * zr; a0i[q] = -k0 * zi; a1r[q] = k1 * zr; a1i[q] = k1 * zi;
  }

  // psi1 = psi0 o (ladder+ring), layout B with phys reg y = W(logical w).
  // Register factor at phys y: f6(y0 ^ l5) * prod_{k=1..5} f_{6+k}(y_k)
  // (the ladder factors g_k(w)=w_k^w_{k-1} ARE the bits of y=W(w)).
  // Lane factor: P(w5) over C(l) bits, w5 = parity(y).
  float P0r = 1.f, P0i = 0.f, P1r = 1.f, P1i = 0.f;
  {
    int cl = l ^ ((l << 1) & 63);
    int cl3 = cl ^ 3;
#pragma unroll
    for (int q = 0; q < 6; ++q) {
      int b = (cl >> q) & 1;
      float fr = b ? a1r[q] : a0r[q], fi = b ? a1i[q] : a0i[q];
      float nr = P0r * fr - P0i * fi; P0i = P0r * fi + P0i * fr; P0r = nr;
      int b2 = (cl3 >> q) & 1;
      float gr = b2 ? a1r[q] : a0r[q], gi = b2 ? a1i[q] : a0i[q];
      float mr = P1r * gr - P1i * gi; P1i = P1r * gi + P1i * gr; P1r = mr;
    }
  }
  float ar[64], ai[64];
  // plain product tree over PHYSICAL bits (R5 fix)
  ar[0] = l5 ? a1r[6] : a0r[6]; ai[0] = l5 ? a1i[6] : a0i[6];
  ar[1] = l5 ? a0r[6] : a1r[6]; ai[1] = l5 ? a0i[6] : a1i[6];
#pragma unroll
  for (int k = 1; k < 6; ++k) {
    float c0r = a0r[6 + k], c0i = a0i[6 + k], c1r = a1r[6 + k], c1i = a1i[6 + k];
#pragma unroll
    for (int m = 0; m < (1 << k); ++m) {
      float xr = ar[m], xi = ai[m];
      ar[m | (1 << k)] = xr * c1r - xi * c1i; ai[m | (1 << k)] = xr * c1i + xi * c1r;
      ar[m] = xr * c0r - xi * c0i; ai[m] = xr * c0i + xi * c0r;
    }
  }
  // lane-part multiply: logical w5 = parity(phys y)
#pragma unroll
  for (int y = 0; y < 64; ++y) {
    float pr = (__popc(y) & 1) ? P1r : P0r;
    float qi = (__popc(y) & 1) ? P1i : P0i;
    float xr = ar[y], xi = ai[y];
    ar[y] = pr * xr - qi * xi; ai[y] = pr * xi + qi * xr;
  }

  // ---- layer 1 ----
  u3Group6W(ar, ai, utabG + (0 * 12 + 6) * 8);   // q6-11 (W-relabeled regs)
  xpBtoA_W(M, l, ar); xpBtoA_W(M, l, ai);        // relabel resolved here
  u3Group6(ar, ai, utabG + (0 * 12 + 0) * 8);    // q0-5 in A
  czA_555(ar, ai, l);
  xpAtoB_m2(M, l, ar); xpAtoB_m2(M, l, ai);      // CX_LONG folded
  // ---- layer 2 ----
  u3Group6(ar, ai, utabG + (1 * 12 + 6) * 8);
  xpBtoA(M, l, ar); xpBtoA(M, l, ai);
  u3Group6(ar, ai, utabG + (1 * 12 + 0) * 8);
  czA_2AA(ar, ai, l);
  xpAtoB_m2(M, l, ar); xpAtoB_m2(M, l, ai);
  // ---- layer 3 ----
  u3Group6(ar, ai, utabG + (2 * 12 + 6) * 8);
  xpBtoA(M, l, ar); xpBtoA(M, l, ai);
  u3Group6(ar, ai, utabG + (2 * 12 + 0) * 8);
  czA_555(ar, ai, l);

  // store transposed with CX_LONG fold: ws[(r<<6) | (l ^ ((r&1)<<5))] = amp
  float* gR = wsStates + (size_t)s * 8192;
  float* gI = gR + 4096;
  const int lA = l, lB = l ^ 32;
#pragma unroll
  for (int r = 0; r < 64; ++r) {
    int idx = (r << 6) | ((r & 1) ? lB : lA);
    gR[idx] = ar[r]; gI[idx] = ai[r];
  }
}

// ---------------- proj: one wave per projection ----------------
__global__ __launch_bounds__(64, 2) void proj_kernel(
    const float* __restrict__ wsStates, const float* __restrict__ ptabG,
    float* __restrict__ featBase) {
  __shared__ float M[4160];
  const int l = threadIdx.x;
  const int bid = blockIdx.x;
  int h, which, s;
  if (bid < 2048) { s = bid >> 2; int pp = bid & 3; h = pp >> 1; which = 1 + (pp & 1); }
  else            { int i = bid - 2048; h = i & 1; s = (((i >> 1) << 6) | 63); which = 0; }
  const int b = s >> 6, t = s & 63;
  const float4* gt = (const float4*)ptabG + (h * 3 + which) * 24;
  const float* stR = wsStates + (size_t)s * 8192 + (l << 6);
  const float* stI = stR + 4096;

  float ar[64], ai[64];
#pragma unroll
  for (int k = 0; k < 16; ++k) {               // contiguous float4 loads (layout B)
    float4 v = ((const float4*)stR)[k];
    ar[4 * k] = v.x; ar[4 * k + 1] = v.y; ar[4 * k + 2] = v.z; ar[4 * k + 3] = v.w;
    float4 u = ((const float4*)stI)[k];
    ai[4 * k] = u.x; ai[4 * k + 1] = u.y; ai[4 * k + 2] = u.z; ai[4 * k + 3] = u.w;
  }

  ryrzGroup6(ar, ai, gt + 6);                  // L0 q6-11 (B)
  xpBtoA(M, l, ar); xpBtoA(M, l, ai);
  ryrzGroup6(ar, ai, gt + 0);                  // L0 q0-5 (A)
  // ladder fold: pre-swap lanes l<->l^1 for odd-parity regs, then pure-fold xpose
#pragma unroll
  for (int r = 0; r < 64; ++r) {
    if (__popc(r) & 1) {
      ar[r] = __shfl_xor(ar[r], 1, 64);
      ai[r] = __shfl_xor(ai[r], 1, 64);
    }
  }
  xpAtoB_map3(M, l, ar); xpAtoB_map3(M, l, ai);
  ryrzGroup6(ar, ai, gt + 18);                 // L1 q6-11 (B)
  xpBtoA(M, l, ar); xpBtoA(M, l, ai);
  ryrzGroup6(ar, ai, gt + 12);                 // L1 q0-5 (A)

  // features in layout A; final ladder folded via prefix parity (R3-validated)
  float acc0 = 0, a7 = 0, a8 = 0, a9 = 0, a10 = 0, a11 = 0;
#pragma unroll
  for (int r = 0; r < 64; ++r) {
    float p = ar[r] * ar[r] + ai[r] * ai[r];
    if (__popc(r & 63) & 1) acc0 -= p; else acc0 += p;
    if (__popc(r & 31) & 1) a7 -= p; else a7 += p;
    if (__popc(r & 15) & 1) a8 -= p; else a8 += p;
    if (__popc(r & 7) & 1)  a9 -= p; else a9 += p;
    if (__popc(r & 3) & 1)  a10 -= p; else a10 += p;
    if (__popc(r & 1) & 1)  a11 -= p; else a11 += p;
  }
  float f[12];
  f[0] = xorf(acc0, (unsigned)(__popc(l & 63) & 1) << 31);
  f[1] = xorf(acc0, (unsigned)(__popc(l & 31) & 1) << 31);
  f[2] = xorf(acc0, (unsigned)(__popc(l & 15) & 1) << 31);
  f[3] = xorf(acc0, (unsigned)(__popc(l & 7) & 1) << 31);
  f[4] = xorf(acc0, (unsigned)(__popc(l & 3) & 1) << 31);
  f[5] = xorf(acc0, (unsigned)(__popc(l & 1) & 1) << 31);
  f[6] = acc0; f[7] = a7; f[8] = a8; f[9] = a9; f[10] = a10; f[11] = a11;
#pragma unroll
  for (int q = 0; q < 12; ++q) {
#pragma unroll
    for (int off = 32; off; off >>= 1) f[q] += __shfl_xor(f[q], off, 64);
  }
  if (l == 0) {
    float* dst;
    if (which == 1)      dst = featBase + (((h << 3) + b) * 64 + t) * 12;
    else if (which == 2) dst = featBase + 12288 + (((h << 3) + b) * 64 + t) * 12;
    else                 dst = featBase + 24576 + ((h << 3) + b) * 12;
#pragma unroll
    for (int q = 0; q < 12; ++q) dst[q] = f[q];
  }
}

// ================= MONO FALLBACK (validated R1/R2 structure) =================
#define PADDED 4224
__device__ __forceinline__ int PD(int j) { return j + (j >> 5); }
__device__ __forceinline__ int mapIdx(int j, int mode) {
  if (mode == 1) { int k = j ^ ((j >> 11) & 1); return k ^ ((k & 0x7FF) << 1); }
  if (mode == 2) { return j ^ ((j & 1) << 11); }
  if (mode == 3) { return j ^ ((j & 0x7FF) << 1); }
  return j;
}
template <int L>
__device__ __forceinline__ int layoutIdx(int tid, int r) {
  if constexpr (L == 0) return (tid << 4) | r;
  else if constexpr (L == 1) return ((tid & 0xF0) << 4) | (r << 4) | (tid & 15);
  else return (r << 8) | tid;
}
template <int L>
__device__ __forceinline__ void ldsRead16(const float* sR, const float* sI, int tid, int mode,
                                          float ar[16], float ai[16]) {
#pragma unroll
  for (int r = 0; r < 16; ++r) {
    int a = PD(mapIdx(layoutIdx<L>(tid, r), mode));
    ar[r] = sR[a]; ai[r] = sI[a];
  }
}
template <int L>
__device__ __forceinline__ void ldsWrite16(float* sR, float* sI, int tid,
                                           const float ar[16], const float ai[16], int czmask) {
#pragma unroll
  for (int r = 0; r < 16; ++r) {
    int j = layoutIdx<L>(tid, r);
    float vr = ar[r], vi = ai[r];
    if (czmask) {
      float sg = (__popc((j & (j >> 1)) & czmask) & 1) ? -1.0f : 1.0f;
      vr *= sg; vi *= sg;
    }
    int a = PD(j);
    sR[a] = vr; sI[a] = vi;
  }
}
__device__ __forceinline__ void applyU34(float ar[16], float ai[16], const float (*ut)[8]) {
#pragma unroll
  for (int b = 0; b < 4; ++b) {
    const float* u = ut[b];
    float u00r = u[0], u01r = u[2], u01i = u[3];
    float u10r = u[4], u10i = u[5], u11r = u[6], u11i = u[7];
#pragma unroll
    for (int m = 0; m < 8; ++m) {
      int p0 = ((m >> b) << (b + 1)) | (m & ((1 << b) - 1));
      int p1 = p0 | (1 << b);
      float x0r = ar[p0], x0i = ai[p0], x1r = ar[p1], x1i = ai[p1];
      ar[p0] = u00r * x0r + u01r * x1r - u01i * x1i;
      ai[p0] = u00r * x0i + u01r * x1i + u01i * x1r;
      ar[p1] = u10r * x0r - u10i * x0i + u11r * x1r - u11i * x1i;
      ai[p1] = u10r * x0i + u10i * x0r + u11r * x1i + u11i * x1r;
    }
  }
}
__device__ __forceinline__ void applyRyRz4(float ar[16], float ai[16], const float4* gt) {
#pragma unroll
  for (int b = 0; b < 4; ++b) {
    float4 g = gt[b];
    float c = g.x, s = g.y, zr = g.z, zi = g.w;
#pragma unroll
    for (int m = 0; m < 8; ++m) {
      int p0 = ((m >> b) << (b + 1)) | (m & ((1 << b) - 1));
      int p1 = p0 | (1 << b);
      float x0r = ar[p0], x0i = ai[p0], x1r = ar[p1], x1i = ai[p1];
      float n0r = c * x0r - s * x1r;
      float n0i = c * x0i - s * x1i;
      float wr  = s * x0r + c * x1r;
      float wi  = s * x0i + c * x1i;
      ar[p0] = n0r;               ai[p0] = n0i;
      ar[p1] = wr * zr - wi * zi; ai[p1] = wr * zi + wi * zr;
    }
  }
}
template <int L>
__device__ __forceinline__ void encPass(float* sR, float* sI, int tid, int mode,
                                        const float (*ut)[8], int czmask) {
  float ar[16], ai[16];
  ldsRead16<L>(sR, sI, tid, mode, ar, ai);
  if (mode != 0) __syncthreads();
  applyU34(ar, ai, ut);
  ldsWrite16<L>(sR, sI, tid, ar, ai, czmask);
  __syncthreads();
}
template <int L>
__device__ __forceinline__ void projPass(float* sR, float* sI, int tid, int mode, const float4* gt) {
  float ar[16], ai[16];
  ldsRead16<L>(sR, sI, tid, mode, ar, ai);
  if (mode != 0) __syncthreads();
  applyRyRz4(ar, ai, gt);
  ldsWrite16<L>(sR, sI, tid, ar, ai, 0);
  __syncthreads();
}
__device__ __forceinline__ void projFinal(const float* sR, const float* sI, int tid,
                                          const float4* gt, float feat[12]) {
  float ar[16], ai[16];
#pragma unroll
  for (int r = 0; r < 16; ++r) {
    int a = PD((r << 8) | tid);
    ar[r] = sR[a]; ai[r] = sI[a];
  }
  applyRyRz4(ar, ai, gt);
  float sp = 0.f, f0 = 0.f, f1 = 0.f, f2 = 0.f, f3 = 0.f;
  int pt = __popc(tid) & 1;
#pragma unroll
  for (int r = 0; r < 16; ++r) {
    float p = ar[r] * ar[r] + ai[r] * ai[r];
    sp += p;
    int tr = r ^ (r << 1); tr ^= (tr << 2);
    f0 += ((pt ^ ((tr >> 3) & 1)) ? -p : p);
    f1 += ((pt ^ ((tr >> 2) & 1)) ? -p : p);
    f2 += ((pt ^ ((tr >> 1) & 1)) ? -p : p);
    f3 += ((pt ^ (tr & 1)) ? -p : p);
  }
  feat[0] = f0; feat[1] = f1; feat[2] = f2; feat[3] = f3;
  int tt = tid ^ (tid << 1); tt ^= (tt << 2); tt ^= (tt << 4);
#pragma unroll
  for (int q = 4; q < 12; ++q)
    feat[q] = ((tt >> (11 - q)) & 1) ? -sp : sp;
}
__device__ __forceinline__ float waveReduce(float v) {
#pragma unroll
  for (int off = 32; off; off >>= 1) v += __shfl_xor(v, off, 64);
  return v;
}
__device__ __forceinline__ void buildQtab(float4* qtab, int tid, float x) {
  if (tid < 12) {
    float th = x * ENC_PI * (float)(tid + 1) / 12.0f;
    float ph = x * ENC_PI / (float)(tid + 1);
    float s, c;  sincosf(0.5f * th, &s, &c);
    float zi, zr; sincosf(0.5f * ph, &zi, &zr);
    float k0 = (c - s) * ENC_RS2, k1 = (c + s) * ENC_RS2;
    qtab[tid] = make_float4(k0 * zr, -k0 * zi, k1 * zr, k1 * zi);
  }
}
__device__ __forceinline__ void buildUtab(float (*utab)[8], int tid, const float* resp) {
  if (tid >= 64 && tid < 100) {
    int i = tid - 64;
    const float* rp = resp + i * 3;
    float st, ct;  sincosf(0.5f * rp[0], &st, &ct);
    float sp2, cp; sincosf(rp[1], &sp2, &cp);
    float sl, cl;  sincosf(rp[2], &sl, &cl);
    float spl, cpl; sincosf(rp[1] + rp[2], &spl, &cpl);
    float* u = utab[i];
    u[0] = ct;       u[1] = 0.0f;
    u[2] = -cl * st; u[3] = -sl * st;
    u[4] = cp * st;  u[5] = sp2 * st;
    u[6] = cpl * ct; u[7] = spl * ct;
  }
}
__device__ __forceinline__ void initProduct(float* sRe, float* sIm, int tid, const float4* qtab) {
  float pr, pi;
  { float4 g = qtab[4]; int sb = tid & 1; pr = sb ? g.z : g.x; pi = sb ? g.w : g.y; }
#pragma unroll
  for (int q = 5; q < 12; ++q) {
    float4 g = qtab[q];
    int sb = (tid >> (q - 4)) & 1;
    float fr = sb ? g.z : g.x, fi = sb ? g.w : g.y;
    float nr = pr * fr - pi * fi;
    pi = pr * fi + pi * fr; pr = nr;
  }
  float4 g0 = qtab[0], g1 = qtab[1], g2 = qtab[2], g3 = qtab[3];
  float c01r[4], c01i[4], c23r[4], c23i[4];
#pragma unroll
  for (int i2 = 0; i2 < 4; ++i2) {
    float f0r = (i2 & 1) ? g0.z : g0.x, f0i = (i2 & 1) ? g0.w : g0.y;
    float f1r = (i2 & 2) ? g1.z : g1.x, f1i = (i2 & 2) ? g1.w : g1.y;
    c01r[i2] = f0r * f1r - f0i * f1i; c01i[i2] = f0r * f1i + f0i * f1r;
    float f2r = (i2 & 1) ? g2.z : g2.x, f2i = (i2 & 1) ? g2.w : g2.y;
    float f3r = (i2 & 2) ? g3.z : g3.x, f3i = (i2 & 2) ? g3.w : g3.y;
    c23r[i2] = f2r * f3r - f2i * f3i; c23i[i2] = f2r * f3i + f2i * f3r;
  }
#pragma unroll
  for (int r = 0; r < 16; ++r) {
    float lr = c01r[r & 3] * c23r[r >> 2] - c01i[r & 3] * c23i[r >> 2];
    float li = c01r[r & 3] * c23i[r >> 2] + c01i[r & 3] * c23r[r >> 2];
    int a = PD((tid << 4) | r);
    sRe[a] = pr * lr - pi * li;
    sIm[a] = pr * li + pi * lr;
  }
}
__device__ __forceinline__ void buildPtab(float4* ptab, int tid, const float* hp) {
  if (tid < 24) {
    int k = tid * 2;
    float s, c;  sincosf(0.5f * hp[k], &s, &c);
    float zi, zr; sincosf(hp[k + 1], &zi, &zr);
    ptab[tid] = make_float4(c, s, zr, zi);
  }
}
__global__ __launch_bounds__(256, 2) void qstates_mono(
    const float* __restrict__ seq, const float* __restrict__ resp,
    const float* __restrict__ hparams, float* __restrict__ featBase) {
  __shared__ float sRe[PADDED], sIm[PADDED];
  __shared__ float4 qtab[12];
  __shared__ float utab[36][8];
  __shared__ float4 ptab[24];
  __shared__ float red[4][12];
  const int tid = threadIdx.x;
  const int blk = blockIdx.x;
  const int b = blk >> 6, t = blk & 63;
  const float x = seq[blk];
  buildQtab(qtab, tid, x);
  buildUtab(utab, tid, resp);
  __syncthreads();
  initProduct(sRe, sIm, tid, qtab);
  __syncthreads();
  for (int ly = 0; ly < 3; ++ly) {
    int czm = (ly & 1) ? 0x2AA : 0x555;
    encPass<0>(sRe, sIm, tid, (ly == 0) ? 1 : 2, &utab[ly * 12], 0);
    encPass<1>(sRe, sIm, tid, 0, &utab[ly * 12 + 4], 0);
    encPass<2>(sRe, sIm, tid, 0, &utab[ly * 12 + 8], czm);
  }
  float encR[16], encI[16];
#pragma unroll
  for (int r = 0; r < 16; ++r) {
    int j = (tid << 4) | r;
    int a = PD(j ^ ((j & 1) << 11));
    encR[r] = sRe[a]; encI[r] = sIm[a];
  }
  const int nproj = (t == 63) ? 6 : 4;
  for (int pj = 0; pj < nproj; ++pj) {
    int h, which;
    if (pj < 4) { h = pj >> 1; which = (pj & 1) ? 2 : 1; }
    else        { h = pj - 4;  which = 0; }
    buildPtab(ptab, tid, hparams + (h * 3 + which) * 48);
    __syncthreads();
    float ar[16], ai[16];
#pragma unroll
    for (int r = 0; r < 16; ++r) { ar[r] = encR[r]; ai[r] = encI[r]; }
    applyRyRz4(ar, ai, &ptab[0]);
    ldsWrite16<0>(sRe, sIm, tid, ar, ai, 0);
    __syncthreads();
    projPass<1>(sRe, sIm, tid, 0, &ptab[4]);
    projPass<2>(sRe, sIm, tid, 0, &ptab[8]);
    projPass<0>(sRe, sIm, tid, 3, &ptab[12]);
    projPass<1>(sRe, sIm, tid, 0, &ptab[16]);
    float feat[12];
    projFinal(sRe, sIm, tid, &ptab[20], feat);
#pragma unroll
    for (int q = 0; q < 12; ++q) feat[q] = waveReduce(feat[q]);
    int wid = tid >> 6;
    if ((tid & 63) == 0) {
#pragma unroll
      for (int q = 0; q < 12; ++q) red[wid][q] = feat[q];
    }
    __syncthreads();
    if (tid < 12) {
      float v = red[0][tid] + red[1][tid] + red[2][tid] + red[3][tid];
      float* dst;
      if (which == 1)      dst = featBase + (((h << 3) + b) * 64 + t) * 12;
      else if (which == 2) dst = featBase + 12288 + (((h << 3) + b) * 64 + t) * 12;
      else                 dst = featBase + 24576 + ((h << 3) + b) * 12;
      dst[tid] = v;
    }
    __syncthreads();
  }
}

// ================= HEAD =================
__global__ __launch_bounds__(64) void qhead_kernel(
    const float* __restrict__ featBase,
    const float* __restrict__ W1, const float* __restrict__ b1,
    const float* __restrict__ W2, const float* __restrict__ b2,
    float* __restrict__ out) {
  __shared__ float feats[24];
  __shared__ float hdn[48];
  const int b = blockIdx.x;
  const int lane = threadIdx.x;
  const float* Kf = featBase;
  const float* Vf = featBase + 12288;
  const float* Qf = featBase + 24576;
  for (int h = 0; h < 2; ++h) {
    const float* q  = Qf + ((h << 3) + b) * 12;
    const float* kr = Kf + ((((h << 3) + b) << 6) + lane) * 12;
    float dot = 0.f;
#pragma unroll
    for (int d = 0; d < 12; ++d) dot += q[d] * kr[d];
    dot *= 0.288675134594812882f;
    float mx = dot;
#pragma unroll
    for (int off = 32; off; off >>= 1) mx = fmaxf(mx, __shfl_xor(mx, off, 64));
    float e = expf(dot - mx);
    float se = e;
#pragma unroll
    for (int off = 32; off; off >>= 1) se += __shfl_xor(se, off, 64);
    float a = e / se;
    const float* vr = Vf + ((((h << 3) + b) << 6) + lane) * 12;
#pragma unroll
    for (int d = 0; d < 12; ++d) {
      float v = a * vr[d];
#pragma unroll
      for (int off = 32; off; off >>= 1) v += __shfl_xor(v, off, 64);
      if (lane == 0) feats[h * 12 + d] = v;
    }
  }
  __syncthreads();
  if (lane < 48) {
    float acc = b1[lane];
#pragma unroll
    for (int f = 0; f < 24; ++f) acc += feats[f] * W1[f * 48 + lane];
    hdn[lane] = 0.5f * acc * (1.0f + erff(acc * 0.70710678118654752440f));
  }
  __syncthreads();
  if (lane < 4) {
    float acc = b2[lane];
#pragma unroll
    for (int k = 0; k < 48; ++k) acc += hdn[k] * W2[k * 4 + lane];
    out[(b << 2) | lane] = acc;
  }
}

extern "C" void kernel_launch(void* const* d_in, const int* in_sizes, int n_in,
                              void* d_out, int out_size, void* d_ws, size_t ws_size,
                              hipStream_t stream) {
  const float* seq     = (const float*)d_in[0];
  const float* resp    = (const float*)d_in[1];
  const float* hparams = (const float*)d_in[2];
  const float* W1      = (const float*)d_in[3];
  const float* b1      = (const float*)d_in[4];
  const float* W2      = (const float*)d_in[5];
  const float* b2      = (const float*)d_in[6];
  float* out = (float*)d_out;
  float* ws  = (float*)d_ws;

  const size_t needSplit = (size_t)WS_TOTAL * sizeof(float);
  if (ws_size >= needSplit) {
    float* wsStates = ws;
    float* featBase = ws + WS_FEAT;
    float* ptabG    = ws + WS_PTAB;
    float* utabG    = ws + WS_UTAB;
    hipLaunchKernelGGL(prep_kernel, dim3(1), dim3(256), 0, stream, hparams, resp, ws);
    hipLaunchKernelGGL(enc_kernel, dim3(512), dim3(64), 0, stream, seq, utabG, wsStates);
    hipLaunchKernelGGL(proj_kernel, dim3(2064), dim3(64), 0, stream, wsStates, ptabG, featBase);
    hipLaunchKernelGGL(qhead_kernel, dim3(8), dim3(64), 0, stream, featBase, W1, b1, W2, b2, out);
  } else {
    hipLaunchKernelGGL(qstates_mono, dim3(512), dim3(256), 0, stream, seq, resp, hparams, ws);
    hipLaunchKernelGGL(qhead_kernel, dim3(8), dim3(64), 0, stream, ws, W1, b1, W2, b2, out);
  }
}

// Round 6
// 219.113 us; speedup vs baseline: 2.2642x; 2.2642x over previous
//
#include <hip/hip_runtime.h>
#include <hip/hip_bf16.h>

// 12-qubit statevector pipeline, fp32.
// prep (gate tables) -> enc (R2-validated, 512 x 256t) ->
// proj (single-LDS-plane re-sequencing of R2's validated passes, 2064 x 256t)
// -> head. Mono fallback if ws small.

// ---------------- ws layout (floats) ----------------
#define N_STATE_F (512 * 8192)
#define WS_FEAT   N_STATE_F               // K 12288 | V 12288 | Q 192
#define WS_PTAB   (WS_FEAT + 24768)       // 144 gates * 4
#define WS_TOTAL  (WS_PTAB + 576)

#define ENC_PI 3.14159265358979323846f
#define ENC_RS2 0.70710678118654752440f

// ---------------- shared index helpers (R1/R2-validated) ----------------
#define PADDED 4224
__device__ __forceinline__ int PD(int j) { return j + (j >> 5); }
// mode 0: identity; 1: encode ladder+ring; 2: CX_LONG; 3: ladder only
__device__ __forceinline__ int mapIdx(int j, int mode) {
  if (mode == 1) { int k = j ^ ((j >> 11) & 1); return k ^ ((k & 0x7FF) << 1); }
  if (mode == 2) { return j ^ ((j & 1) << 11); }
  if (mode == 3) { return j ^ ((j & 0x7FF) << 1); }
  return j;
}
template <int L>
__device__ __forceinline__ int layoutIdx(int tid, int r) {
  if constexpr (L == 0) return (tid << 4) | r;                                   // bits 0-3 local
  else if constexpr (L == 1) return ((tid & 0xF0) << 4) | (r << 4) | (tid & 15); // bits 4-7 local
  else return (r << 8) | tid;                                                    // bits 8-11 local
}
template <int L>
__device__ __forceinline__ void ldsRead16(const float* sR, const float* sI, int tid, int mode,
                                          float ar[16], float ai[16]) {
#pragma unroll
  for (int r = 0; r < 16; ++r) {
    int a = PD(mapIdx(layoutIdx<L>(tid, r), mode));
    ar[r] = sR[a]; ai[r] = sI[a];
  }
}
template <int L>
__device__ __forceinline__ void ldsWrite16(float* sR, float* sI, int tid,
                                           const float ar[16], const float ai[16], int czmask) {
#pragma unroll
  for (int r = 0; r < 16; ++r) {
    int j = layoutIdx<L>(tid, r);
    float vr = ar[r], vi = ai[r];
    if (czmask) {
      float sg = (__popc((j & (j >> 1)) & czmask) & 1) ? -1.0f : 1.0f;
      vr *= sg; vi *= sg;
    }
    int a = PD(j);
    sR[a] = vr; sI[a] = vi;
  }
}
// 4 U3 gates on local bits 0..3 (u00 real)
__device__ __forceinline__ void applyU34(float ar[16], float ai[16], const float (*ut)[8]) {
#pragma unroll
  for (int b = 0; b < 4; ++b) {
    const float* u = ut[b];
    float u00r = u[0], u01r = u[2], u01i = u[3];
    float u10r = u[4], u10i = u[5], u11r = u[6], u11i = u[7];
#pragma unroll
    for (int m = 0; m < 8; ++m) {
      int p0 = ((m >> b) << (b + 1)) | (m & ((1 << b) - 1));
      int p1 = p0 | (1 << b);
      float x0r = ar[p0], x0i = ai[p0], x1r = ar[p1], x1i = ai[p1];
      ar[p0] = u00r * x0r + u01r * x1r - u01i * x1i;
      ai[p0] = u00r * x0i + u01r * x1i + u01i * x1r;
      ar[p1] = u10r * x0r - u10i * x0i + u11r * x1r - u11i * x1i;
      ai[p1] = u10r * x0i + u10i * x0r + u11r * x1i + u11i * x1r;
    }
  }
}
// 4 fused RY+RZ gates (global phase dropped), gt[b] = {cos t/2, sin t/2, cos phi, sin phi}
__device__ __forceinline__ void applyRyRz4(float ar[16], float ai[16], const float4* gt) {
#pragma unroll
  for (int b = 0; b < 4; ++b) {
    float4 g = gt[b];
    float c = g.x, s = g.y, zr = g.z, zi = g.w;
#pragma unroll
    for (int m = 0; m < 8; ++m) {
      int p0 = ((m >> b) << (b + 1)) | (m & ((1 << b) - 1));
      int p1 = p0 | (1 << b);
      float x0r = ar[p0], x0i = ai[p0], x1r = ar[p1], x1i = ai[p1];
      float n0r = c * x0r - s * x1r;
      float n0i = c * x0i - s * x1i;
      float wr  = s * x0r + c * x1r;
      float wi  = s * x0i + c * x1i;
      ar[p0] = n0r;               ai[p0] = n0i;
      ar[p1] = wr * zr - wi * zi; ai[p1] = wr * zi + wi * zr;
    }
  }
}
template <int L>
__device__ __forceinline__ void encPass(float* sR, float* sI, int tid, int mode,
                                        const float (*ut)[8], int czmask) {
  float ar[16], ai[16];
  ldsRead16<L>(sR, sI, tid, mode, ar, ai);
  if (mode != 0) __syncthreads();
  applyU34(ar, ai, ut);
  ldsWrite16<L>(sR, sI, tid, ar, ai, czmask);
  __syncthreads();
}
__device__ __forceinline__ float waveReduce(float v) {
#pragma unroll
  for (int off = 32; off; off >>= 1) v += __shfl_xor(v, off, 64);
  return v;
}
__device__ __forceinline__ void buildQtab(float4* qtab, int tid, float x) {
  if (tid < 12) {
    float th = x * ENC_PI * (float)(tid + 1) / 12.0f;
    float ph = x * ENC_PI / (float)(tid + 1);
    float s, c;  sincosf(0.5f * th, &s, &c);
    float zi, zr; sincosf(0.5f * ph, &zi, &zr);
    float k0 = (c - s) * ENC_RS2, k1 = (c + s) * ENC_RS2;
    qtab[tid] = make_float4(k0 * zr, -k0 * zi, k1 * zr, k1 * zi);
  }
}
__device__ __forceinline__ void buildUtab(float (*utab)[8], int tid, const float* resp) {
  if (tid >= 64 && tid < 100) {
    int i = tid - 64;
    const float* rp = resp + i * 3;
    float st, ct;  sincosf(0.5f * rp[0], &st, &ct);
    float sp2, cp; sincosf(rp[1], &sp2, &cp);
    float sl, cl;  sincosf(rp[2], &sl, &cl);
    float spl, cpl; sincosf(rp[1] + rp[2], &spl, &cpl);
    float* u = utab[i];
    u[0] = ct;       u[1] = 0.0f;
    u[2] = -cl * st; u[3] = -sl * st;
    u[4] = cp * st;  u[5] = sp2 * st;
    u[6] = cpl * ct; u[7] = spl * ct;
  }
}
__device__ __forceinline__ void initProduct(float* sRe, float* sIm, int tid, const float4* qtab) {
  float pr, pi;
  { float4 g = qtab[4]; int sb = tid & 1; pr = sb ? g.z : g.x; pi = sb ? g.w : g.y; }
#pragma unroll
  for (int q = 5; q < 12; ++q) {
    float4 g = qtab[q];
    int sb = (tid >> (q - 4)) & 1;
    float fr = sb ? g.z : g.x, fi = sb ? g.w : g.y;
    float nr = pr * fr - pi * fi;
    pi = pr * fi + pi * fr; pr = nr;
  }
  float4 g0 = qtab[0], g1 = qtab[1], g2 = qtab[2], g3 = qtab[3];
  float c01r[4], c01i[4], c23r[4], c23i[4];
#pragma unroll
  for (int i2 = 0; i2 < 4; ++i2) {
    float f0r = (i2 & 1) ? g0.z : g0.x, f0i = (i2 & 1) ? g0.w : g0.y;
    float f1r = (i2 & 2) ? g1.z : g1.x, f1i = (i2 & 2) ? g1.w : g1.y;
    c01r[i2] = f0r * f1r - f0i * f1i; c01i[i2] = f0r * f1i + f0i * f1r;
    float f2r = (i2 & 1) ? g2.z : g2.x, f2i = (i2 & 1) ? g2.w : g2.y;
    float f3r = (i2 & 2) ? g3.z : g3.x, f3i = (i2 & 2) ? g3.w : g3.y;
    c23r[i2] = f2r * f3r - f2i * f3i; c23i[i2] = f2r * f3i + f2i * f3r;
  }
#pragma unroll
  for (int r = 0; r < 16; ++r) {
    float lr = c01r[r & 3] * c23r[r >> 2] - c01i[r & 3] * c23i[r >> 2];
    float li = c01r[r & 3] * c23i[r >> 2] + c01i[r & 3] * c23r[r >> 2];
    int a = PD((tid << 4) | r);
    sRe[a] = pr * lr - pi * li;
    sIm[a] = pr * li + pi * lr;
  }
}
__device__ __forceinline__ void buildPtab(float4* ptab, int tid, const float* hp) {
  if (tid < 24) {
    int k = tid * 2;
    float s, c;  sincosf(0.5f * hp[k], &s, &c);
    float zi, zr; sincosf(hp[k + 1], &zi, &zr);
    ptab[tid] = make_float4(c, s, zr, zi);
  }
}

// ---------------- prep: projection gate tables -> ws ----------------
__global__ void prep_kernel(const float* __restrict__ hparams, float* __restrict__ ws) {
  int t = threadIdx.x;
  float4* ptab = (float4*)(ws + WS_PTAB);
  for (int idx = t; idx < 144; idx += 256) {
    int pj = idx / 24, k = idx % 24;
    const float* hp = hparams + pj * 48;
    float s, c;  sincosf(0.5f * hp[2 * k], &s, &c);
    float zi, zr; sincosf(hp[2 * k + 1], &zi, &zr);
    ptab[idx] = make_float4(c, s, zr, zi);
  }
}

// ---------------- enc: R2-validated kernel, verbatim ----------------
__global__ __launch_bounds__(256, 2) void enc_kernel(
    const float* __restrict__ seq, const float* __restrict__ resp,
    float* __restrict__ wsStates) {
  __shared__ float sRe[PADDED], sIm[PADDED];
  __shared__ float4 qtab[12];
  __shared__ float utab[36][8];

  const int tid = threadIdx.x;
  const int blk = blockIdx.x;          // state index s
  const float x = seq[blk];

  buildQtab(qtab, tid, x);
  buildUtab(utab, tid, resp);
  __syncthreads();

  initProduct(sRe, sIm, tid, qtab);
  __syncthreads();

  encPass<0>(sRe, sIm, tid, 1, &utab[0], 0);
  encPass<1>(sRe, sIm, tid, 0, &utab[4], 0);
  encPass<2>(sRe, sIm, tid, 0, &utab[8], 0x555);
  encPass<0>(sRe, sIm, tid, 2, &utab[12], 0);
  encPass<1>(sRe, sIm, tid, 0, &utab[16], 0);
  encPass<2>(sRe, sIm, tid, 0, &utab[20], 0x2AA);
  encPass<0>(sRe, sIm, tid, 2, &utab[24], 0);
  encPass<1>(sRe, sIm, tid, 0, &utab[28], 0);

  // final pass: gates 8-11 (layout2) + CZ(0x555), store with CX_LONG fold
  {
    float ar[16], ai[16];
    ldsRead16<2>(sRe, sIm, tid, 0, ar, ai);
    applyU34(ar, ai, &utab[32]);
    float* gR = wsStates + (size_t)blk * 8192;
    float* gI = gR + 4096;
#pragma unroll
    for (int r = 0; r < 16; ++r) {
      int j = (r << 8) | tid;
      float sg = (__popc((j & (j >> 1)) & 0x555) & 1) ? -1.0f : 1.0f;
      int g = j ^ ((j & 1) << 11);  // involution
      gR[g] = sg * ar[r];
      gI[g] = sg * ai[r];
    }
  }
}

// ---------------- proj: single-LDS-plane re-sequencing of R2 passes ----------------
// perm: state regs stay resident; one 16.9KB plane permutes im then re.
template <int W, int R>
__device__ __forceinline__ void perm16(float* M, int tid, int map,
                                       float (&ar)[16], float (&ai)[16]) {
#pragma unroll
  for (int r = 0; r < 16; ++r) M[PD(layoutIdx<W>(tid, r))] = ai[r];
  __syncthreads();
#pragma unroll
  for (int r = 0; r < 16; ++r) ai[r] = M[PD(mapIdx(layoutIdx<R>(tid, r), map))];
  __syncthreads();
#pragma unroll
  for (int r = 0; r < 16; ++r) M[PD(layoutIdx<W>(tid, r))] = ar[r];
  __syncthreads();
#pragma unroll
  for (int r = 0; r < 16; ++r) ar[r] = M[PD(mapIdx(layoutIdx<R>(tid, r), map))];
  __syncthreads();
}

__global__ __launch_bounds__(256, 8) void proj_kernel(
    const float* __restrict__ wsStates, const float* __restrict__ ptabG,
    float* __restrict__ featBase) {
  __shared__ float M[PADDED];
  __shared__ float4 ptab[24];
  __shared__ float red[4][12];

  const int tid = threadIdx.x;
  const int bid = blockIdx.x;
  int h, which, s;
  if (bid < 2048) { s = bid >> 2; int pp = bid & 3; h = pp >> 1; which = 1 + (pp & 1); }
  else            { int i = bid - 2048; h = i & 1; s = (((i >> 1) << 6) | 63); which = 0; }
  const int b = s >> 6, t = s & 63;

  if (tid < 24) ptab[tid] = ((const float4*)ptabG)[(h * 3 + which) * 24 + tid];

  // coalesced state load: thread owns j = 16*tid .. 16*tid+15 (layout 0)
  float ar[16], ai[16];
  const float4* pR = (const float4*)(wsStates + (size_t)s * 8192 + (tid << 4));
  const float4* pI = (const float4*)(wsStates + (size_t)s * 8192 + 4096 + (tid << 4));
#pragma unroll
  for (int k = 0; k < 4; ++k) {
    float4 vr = pR[k], vi = pI[k];
    ar[4 * k] = vr.x; ar[4 * k + 1] = vr.y; ar[4 * k + 2] = vr.z; ar[4 * k + 3] = vr.w;
    ai[4 * k] = vi.x; ai[4 * k + 1] = vi.y; ai[4 * k + 2] = vi.z; ai[4 * k + 3] = vi.w;
  }
  __syncthreads();  // ptab ready

  applyRyRz4(ar, ai, &ptab[0]);          // L0 q0-3   (layout 0)
  perm16<0, 1>(M, tid, 0, ar, ai);
  applyRyRz4(ar, ai, &ptab[4]);          // L0 q4-7   (layout 1)
  perm16<1, 2>(M, tid, 0, ar, ai);
  applyRyRz4(ar, ai, &ptab[8]);          // L0 q8-11  (layout 2)
  perm16<2, 0>(M, tid, 3, ar, ai);       // ladder fold (R2-validated mode 3)
  applyRyRz4(ar, ai, &ptab[12]);         // L1 q0-3   (layout 0)
  perm16<0, 1>(M, tid, 0, ar, ai);
  applyRyRz4(ar, ai, &ptab[16]);         // L1 q4-7   (layout 1)
  perm16<1, 2>(M, tid, 0, ar, ai);
  applyRyRz4(ar, ai, &ptab[20]);         // L1 q8-11  (layout 2)

  // features (R2 projFinal sign math, verbatim; regs are layout 2)
  float sp = 0.f, f0 = 0.f, f1 = 0.f, f2 = 0.f, f3 = 0.f;
  int pt = __popc(tid) & 1;
#pragma unroll
  for (int r = 0; r < 16; ++r) {
    float p = ar[r] * ar[r] + ai[r] * ai[r];
    sp += p;
    int tr = r ^ (r << 1); tr ^= (tr << 2);  // 4-bit prefix-xor of r
    f0 += ((pt ^ ((tr >> 3) & 1)) ? -p : p);
    f1 += ((pt ^ ((tr >> 2) & 1)) ? -p : p);
    f2 += ((pt ^ ((tr >> 1) & 1)) ? -p : p);
    f3 += ((pt ^ (tr & 1)) ? -p : p);
  }
  float feat[12];
  feat[0] = f0; feat[1] = f1; feat[2] = f2; feat[3] = f3;
  int tt = tid ^ (tid << 1); tt ^= (tt << 2); tt ^= (tt << 4);  // 8-bit prefix-xor
#pragma unroll
  for (int q = 4; q < 12; ++q)
    feat[q] = ((tt >> (11 - q)) & 1) ? -sp : sp;

#pragma unroll
  for (int q = 0; q < 12; ++q) feat[q] = waveReduce(feat[q]);
  int wid = tid >> 6;
  if ((tid & 63) == 0) {
#pragma unroll
    for (int q = 0; q < 12; ++q) red[wid][q] = feat[q];
  }
  __syncthreads();
  if (tid < 12) {
    float v = red[0][tid] + red[1][tid] + red[2][tid] + red[3][tid];
    float* dst;
    if (which == 1)      dst = featBase + (((h << 3) + b) * 64 + t) * 12;
    else if (which == 2) dst = featBase + 12288 + (((h << 3) + b) * 64 + t) * 12;
    else                 dst = featBase + 24576 + ((h << 3) + b) * 12;
    dst[tid] = v;
  }
}

// ================= MONO FALLBACK (R1-validated) =================
template <int L>
__device__ __forceinline__ void projPassM(float* sR, float* sI, int tid, int mode, const float4* gt) {
  float ar[16], ai[16];
  ldsRead16<L>(sR, sI, tid, mode, ar, ai);
  if (mode != 0) __syncthreads();
  applyRyRz4(ar, ai, gt);
  ldsWrite16<L>(sR, sI, tid, ar, ai, 0);
  __syncthreads();
}
__device__ __forceinline__ void projFinalM(const float* sR, const float* sI, int tid,
                                           const float4* gt, float feat[12]) {
  float ar[16], ai[16];
#pragma unroll
  for (int r = 0; r < 16; ++r) {
    int a = PD((r << 8) | tid);
    ar[r] = sR[a]; ai[r] = sI[a];
  }
  applyRyRz4(ar, ai, gt);
  float sp = 0.f, f0 = 0.f, f1 = 0.f, f2 = 0.f, f3 = 0.f;
  int pt = __popc(tid) & 1;
#pragma unroll
  for (int r = 0; r < 16; ++r) {
    float p = ar[r] * ar[r] + ai[r] * ai[r];
    sp += p;
    int tr = r ^ (r << 1); tr ^= (tr << 2);
    f0 += ((pt ^ ((tr >> 3) & 1)) ? -p : p);
    f1 += ((pt ^ ((tr >> 2) & 1)) ? -p : p);
    f2 += ((pt ^ ((tr >> 1) & 1)) ? -p : p);
    f3 += ((pt ^ (tr & 1)) ? -p : p);
  }
  feat[0] = f0; feat[1] = f1; feat[2] = f2; feat[3] = f3;
  int tt = tid ^ (tid << 1); tt ^= (tt << 2); tt ^= (tt << 4);
#pragma unroll
  for (int q = 4; q < 12; ++q)
    feat[q] = ((tt >> (11 - q)) & 1) ? -sp : sp;
}
__global__ __launch_bounds__(256, 2) void qstates_mono(
    const float* __restrict__ seq, const float* __restrict__ resp,
    const float* __restrict__ hparams, float* __restrict__ featBase) {
  __shared__ float sRe[PADDED], sIm[PADDED];
  __shared__ float4 qtab[12];
  __shared__ float utab[36][8];
  __shared__ float4 ptab[24];
  __shared__ float red[4][12];
  const int tid = threadIdx.x;
  const int blk = blockIdx.x;
  const int b = blk >> 6, t = blk & 63;
  const float x = seq[blk];
  buildQtab(qtab, tid, x);
  buildUtab(utab, tid, resp);
  __syncthreads();
  initProduct(sRe, sIm, tid, qtab);
  __syncthreads();
  for (int ly = 0; ly < 3; ++ly) {
    int czm = (ly & 1) ? 0x2AA : 0x555;
    encPass<0>(sRe, sIm, tid, (ly == 0) ? 1 : 2, &utab[ly * 12], 0);
    encPass<1>(sRe, sIm, tid, 0, &utab[ly * 12 + 4], 0);
    encPass<2>(sRe, sIm, tid, 0, &utab[ly * 12 + 8], czm);
  }
  float encR[16], encI[16];
#pragma unroll
  for (int r = 0; r < 16; ++r) {
    int j = (tid << 4) | r;
    int a = PD(j ^ ((j & 1) << 11));
    encR[r] = sRe[a]; encI[r] = sIm[a];
  }
  const int nproj = (t == 63) ? 6 : 4;
  for (int pj = 0; pj < nproj; ++pj) {
    int h, which;
    if (pj < 4) { h = pj >> 1; which = (pj & 1) ? 2 : 1; }
    else        { h = pj - 4;  which = 0; }
    buildPtab(ptab, tid, hparams + (h * 3 + which) * 48);
    __syncthreads();
    float ar[16], ai[16];
#pragma unroll
    for (int r = 0; r < 16; ++r) { ar[r] = encR[r]; ai[r] = encI[r]; }
    applyRyRz4(ar, ai, &ptab[0]);
    ldsWrite16<0>(sRe, sIm, tid, ar, ai, 0);
    __syncthreads();
    projPassM<1>(sRe, sIm, tid, 0, &ptab[4]);
    projPassM<2>(sRe, sIm, tid, 0, &ptab[8]);
    projPassM<0>(sRe, sIm, tid, 3, &ptab[12]);
    projPassM<1>(sRe, sIm, tid, 0, &ptab[16]);
    float feat[12];
    projFinalM(sRe, sIm, tid, &ptab[20], feat);
#pragma unroll
    for (int q = 0; q < 12; ++q) feat[q] = waveReduce(feat[q]);
    int wid = tid >> 6;
    if ((tid & 63) == 0) {
#pragma unroll
      for (int q = 0; q < 12; ++q) red[wid][q] = feat[q];
    }
    __syncthreads();
    if (tid < 12) {
      float v = red[0][tid] + red[1][tid] + red[2][tid] + red[3][tid];
      float* dst;
      if (which == 1)      dst = featBase + (((h << 3) + b) * 64 + t) * 12;
      else if (which == 2) dst = featBase + 12288 + (((h << 3) + b) * 64 + t) * 12;
      else                 dst = featBase + 24576 + ((h << 3) + b) * 12;
      dst[tid] = v;
    }
    __syncthreads();
  }
}

// ================= HEAD =================
__global__ __launch_bounds__(64) void qhead_kernel(
    const float* __restrict__ featBase,
    const float* __restrict__ W1, const float* __restrict__ b1,
    const float* __restrict__ W2, const float* __restrict__ b2,
    float* __restrict__ out) {
  __shared__ float feats[24];
  __shared__ float hdn[48];
  const int b = blockIdx.x;
  const int lane = threadIdx.x;
  const float* Kf = featBase;
  const float* Vf = featBase + 12288;
  const float* Qf = featBase + 24576;
  for (int h = 0; h < 2; ++h) {
    const float* q  = Qf + ((h << 3) + b) * 12;
    const float* kr = Kf + ((((h << 3) + b) << 6) + lane) * 12;
    float dot = 0.f;
#pragma unroll
    for (int d = 0; d < 12; ++d) dot += q[d] * kr[d];
    dot *= 0.288675134594812882f;  // 1/sqrt(12); mask row 63 all-zero
    float mx = dot;
#pragma unroll
    for (int off = 32; off; off >>= 1) mx = fmaxf(mx, __shfl_xor(mx, off, 64));
    float e = expf(dot - mx);
    float se = e;
#pragma unroll
    for (int off = 32; off; off >>= 1) se += __shfl_xor(se, off, 64);
    float a = e / se;
    const float* vr = Vf + ((((h << 3) + b) << 6) + lane) * 12;
#pragma unroll
    for (int d = 0; d < 12; ++d) {
      float v = a * vr[d];
#pragma unroll
      for (int off = 32; off; off >>= 1) v += __shfl_xor(v, off, 64);
      if (lane == 0) feats[h * 12 + d] = v;
    }
  }
  __syncthreads();
  if (lane < 48) {
    float acc = b1[lane];
#pragma unroll
    for (int f = 0; f < 24; ++f) acc += feats[f] * W1[f * 48 + lane];
    hdn[lane] = 0.5f * acc * (1.0f + erff(acc * 0.70710678118654752440f));
  }
  __syncthreads();
  if (lane < 4) {
    float acc = b2[lane];
#pragma unroll
    for (int k = 0; k < 48; ++k) acc += hdn[k] * W2[k * 4 + lane];
    out[(b << 2) | lane] = acc;
  }
}

extern "C" void kernel_launch(void* const* d_in, const int* in_sizes, int n_in,
                              void* d_out, int out_size, void* d_ws, size_t ws_size,
                              hipStream_t stream) {
  const float* seq     = (const float*)d_in[0];
  const float* resp    = (const float*)d_in[1];
  const float* hparams = (const float*)d_in[2];
  const float* W1      = (const float*)d_in[3];
  const float* b1      = (const float*)d_in[4];
  const float* W2      = (const float*)d_in[5];
  const float* b2      = (const float*)d_in[6];
  float* out = (float*)d_out;
  float* ws  = (float*)d_ws;

  const size_t needSplit = (size_t)WS_TOTAL * sizeof(float);
  if (ws_size >= needSplit) {
    float* wsStates = ws;
    float* featBase = ws + WS_FEAT;
    float* ptabG    = ws + WS_PTAB;
    hipLaunchKernelGGL(prep_kernel, dim3(1), dim3(256), 0, stream, hparams, ws);
    hipLaunchKernelGGL(enc_kernel, dim3(512), dim3(256), 0, stream, seq, resp, wsStates);
    hipLaunchKernelGGL(proj_kernel, dim3(2064), dim3(256), 0, stream, wsStates, ptabG, featBase);
    hipLaunchKernelGGL(qhead_kernel, dim3(8), dim3(64), 0, stream, featBase, W1, b1, W2, b2, out);
  } else {
    hipLaunchKernelGGL(qstates_mono, dim3(512), dim3(256), 0, stream, seq, resp, hparams, ws);
    hipLaunchKernelGGL(qhead_kernel, dim3(8), dim3(64), 0, stream, ws, W1, b1, W2, b2, out);
  }
}

// Round 7
// 153.659 us; speedup vs baseline: 3.2287x; 1.4260x over previous
//
#include <hip/hip_runtime.h>
#include <hip/hip_bf16.h>

// 12-qubit statevector pipeline, fp32.
// prep (gate tables) -> enc (R2-validated, 512 x 256t) ->
// proj (single-LDS-plane re-sequencing; R7 fix: launch_bounds(256,4) so the
// 32-float register state never spills — R6's (256,8) capped VGPR at 32 and
// pushed 370MB of scratch traffic) -> head. Mono fallback if ws small.

// ---------------- ws layout (floats) ----------------
#define N_STATE_F (512 * 8192)
#define WS_FEAT   N_STATE_F               // K 12288 | V 12288 | Q 192
#define WS_PTAB   (WS_FEAT + 24768)       // 144 gates * 4
#define WS_TOTAL  (WS_PTAB + 576)

#define ENC_PI 3.14159265358979323846f
#define ENC_RS2 0.70710678118654752440f

// ---------------- shared index helpers (R1/R2-validated) ----------------
#define PADDED 4224
__device__ __forceinline__ int PD(int j) { return j + (j >> 5); }
// mode 0: identity; 1: encode ladder+ring; 2: CX_LONG; 3: ladder only
__device__ __forceinline__ int mapIdx(int j, int mode) {
  if (mode == 1) { int k = j ^ ((j >> 11) & 1); return k ^ ((k & 0x7FF) << 1); }
  if (mode == 2) { return j ^ ((j & 1) << 11); }
  if (mode == 3) { return j ^ ((j & 0x7FF) << 1); }
  return j;
}
template <int L>
__device__ __forceinline__ int layoutIdx(int tid, int r) {
  if constexpr (L == 0) return (tid << 4) | r;                                   // bits 0-3 local
  else if constexpr (L == 1) return ((tid & 0xF0) << 4) | (r << 4) | (tid & 15); // bits 4-7 local
  else return (r << 8) | tid;                                                    // bits 8-11 local
}
template <int L>
__device__ __forceinline__ void ldsRead16(const float* sR, const float* sI, int tid, int mode,
                                          float ar[16], float ai[16]) {
#pragma unroll
  for (int r = 0; r < 16; ++r) {
    int a = PD(mapIdx(layoutIdx<L>(tid, r), mode));
    ar[r] = sR[a]; ai[r] = sI[a];
  }
}
template <int L>
__device__ __forceinline__ void ldsWrite16(float* sR, float* sI, int tid,
                                           const float ar[16], const float ai[16], int czmask) {
#pragma unroll
  for (int r = 0; r < 16; ++r) {
    int j = layoutIdx<L>(tid, r);
    float vr = ar[r], vi = ai[r];
    if (czmask) {
      float sg = (__popc((j & (j >> 1)) & czmask) & 1) ? -1.0f : 1.0f;
      vr *= sg; vi *= sg;
    }
    int a = PD(j);
    sR[a] = vr; sI[a] = vi;
  }
}
// 4 U3 gates on local bits 0..3 (u00 real)
__device__ __forceinline__ void applyU34(float ar[16], float ai[16], const float (*ut)[8]) {
#pragma unroll
  for (int b = 0; b < 4; ++b) {
    const float* u = ut[b];
    float u00r = u[0], u01r = u[2], u01i = u[3];
    float u10r = u[4], u10i = u[5], u11r = u[6], u11i = u[7];
#pragma unroll
    for (int m = 0; m < 8; ++m) {
      int p0 = ((m >> b) << (b + 1)) | (m & ((1 << b) - 1));
      int p1 = p0 | (1 << b);
      float x0r = ar[p0], x0i = ai[p0], x1r = ar[p1], x1i = ai[p1];
      ar[p0] = u00r * x0r + u01r * x1r - u01i * x1i;
      ai[p0] = u00r * x0i + u01r * x1i + u01i * x1r;
      ar[p1] = u10r * x0r - u10i * x0i + u11r * x1r - u11i * x1i;
      ai[p1] = u10r * x0i + u10i * x0r + u11r * x1i + u11i * x1r;
    }
  }
}
// 4 fused RY+RZ gates (global phase dropped), gt[b] = {cos t/2, sin t/2, cos phi, sin phi}
__device__ __forceinline__ void applyRyRz4(float ar[16], float ai[16], const float4* gt) {
#pragma unroll
  for (int b = 0; b < 4; ++b) {
    float4 g = gt[b];
    float c = g.x, s = g.y, zr = g.z, zi = g.w;
#pragma unroll
    for (int m = 0; m < 8; ++m) {
      int p0 = ((m >> b) << (b + 1)) | (m & ((1 << b) - 1));
      int p1 = p0 | (1 << b);
      float x0r = ar[p0], x0i = ai[p0], x1r = ar[p1], x1i = ai[p1];
      float n0r = c * x0r - s * x1r;
      float n0i = c * x0i - s * x1i;
      float wr  = s * x0r + c * x1r;
      float wi  = s * x0i + c * x1i;
      ar[p0] = n0r;               ai[p0] = n0i;
      ar[p1] = wr * zr - wi * zi; ai[p1] = wr * zi + wi * zr;
    }
  }
}
template <int L>
__device__ __forceinline__ void encPass(float* sR, float* sI, int tid, int mode,
                                        const float (*ut)[8], int czmask) {
  float ar[16], ai[16];
  ldsRead16<L>(sR, sI, tid, mode, ar, ai);
  if (mode != 0) __syncthreads();
  applyU34(ar, ai, ut);
  ldsWrite16<L>(sR, sI, tid, ar, ai, czmask);
  __syncthreads();
}
__device__ __forceinline__ float waveReduce(float v) {
#pragma unroll
  for (int off = 32; off; off >>= 1) v += __shfl_xor(v, off, 64);
  return v;
}
__device__ __forceinline__ void buildQtab(float4* qtab, int tid, float x) {
  if (tid < 12) {
    float th = x * ENC_PI * (float)(tid + 1) / 12.0f;
    float ph = x * ENC_PI / (float)(tid + 1);
    float s, c;  sincosf(0.5f * th, &s, &c);
    float zi, zr; sincosf(0.5f * ph, &zi, &zr);
    float k0 = (c - s) * ENC_RS2, k1 = (c + s) * ENC_RS2;
    qtab[tid] = make_float4(k0 * zr, -k0 * zi, k1 * zr, k1 * zi);
  }
}
__device__ __forceinline__ void buildUtab(float (*utab)[8], int tid, const float* resp) {
  if (tid >= 64 && tid < 100) {
    int i = tid - 64;
    const float* rp = resp + i * 3;
    float st, ct;  sincosf(0.5f * rp[0], &st, &ct);
    float sp2, cp; sincosf(rp[1], &sp2, &cp);
    float sl, cl;  sincosf(rp[2], &sl, &cl);
    float spl, cpl; sincosf(rp[1] + rp[2], &spl, &cpl);
    float* u = utab[i];
    u[0] = ct;       u[1] = 0.0f;
    u[2] = -cl * st; u[3] = -sl * st;
    u[4] = cp * st;  u[5] = sp2 * st;
    u[6] = cpl * ct; u[7] = spl * ct;
  }
}
__device__ __forceinline__ void initProduct(float* sRe, float* sIm, int tid, const float4* qtab) {
  float pr, pi;
  { float4 g = qtab[4]; int sb = tid & 1; pr = sb ? g.z : g.x; pi = sb ? g.w : g.y; }
#pragma unroll
  for (int q = 5; q < 12; ++q) {
    float4 g = qtab[q];
    int sb = (tid >> (q - 4)) & 1;
    float fr = sb ? g.z : g.x, fi = sb ? g.w : g.y;
    float nr = pr * fr - pi * fi;
    pi = pr * fi + pi * fr; pr = nr;
  }
  float4 g0 = qtab[0], g1 = qtab[1], g2 = qtab[2], g3 = qtab[3];
  float c01r[4], c01i[4], c23r[4], c23i[4];
#pragma unroll
  for (int i2 = 0; i2 < 4; ++i2) {
    float f0r = (i2 & 1) ? g0.z : g0.x, f0i = (i2 & 1) ? g0.w : g0.y;
    float f1r = (i2 & 2) ? g1.z : g1.x, f1i = (i2 & 2) ? g1.w : g1.y;
    c01r[i2] = f0r * f1r - f0i * f1i; c01i[i2] = f0r * f1i + f0i * f1r;
    float f2r = (i2 & 1) ? g2.z : g2.x, f2i = (i2 & 1) ? g2.w : g2.y;
    float f3r = (i2 & 2) ? g3.z : g3.x, f3i = (i2 & 2) ? g3.w : g3.y;
    c23r[i2] = f2r * f3r - f2i * f3i; c23i[i2] = f2r * f3i + f2i * f3r;
  }
#pragma unroll
  for (int r = 0; r < 16; ++r) {
    float lr = c01r[r & 3] * c23r[r >> 2] - c01i[r & 3] * c23i[r >> 2];
    float li = c01r[r & 3] * c23i[r >> 2] + c01i[r & 3] * c23r[r >> 2];
    int a = PD((tid << 4) | r);
    sRe[a] = pr * lr - pi * li;
    sIm[a] = pr * li + pi * lr;
  }
}
__device__ __forceinline__ void buildPtab(float4* ptab, int tid, const float* hp) {
  if (tid < 24) {
    int k = tid * 2;
    float s, c;  sincosf(0.5f * hp[k], &s, &c);
    float zi, zr; sincosf(hp[k + 1], &zi, &zr);
    ptab[tid] = make_float4(c, s, zr, zi);
  }
}

// ---------------- prep: projection gate tables -> ws ----------------
__global__ void prep_kernel(const float* __restrict__ hparams, float* __restrict__ ws) {
  int t = threadIdx.x;
  float4* ptab = (float4*)(ws + WS_PTAB);
  for (int idx = t; idx < 144; idx += 256) {
    int pj = idx / 24, k = idx % 24;
    const float* hp = hparams + pj * 48;
    float s, c;  sincosf(0.5f * hp[2 * k], &s, &c);
    float zi, zr; sincosf(hp[2 * k + 1], &zi, &zr);
    ptab[idx] = make_float4(c, s, zr, zi);
  }
}

// ---------------- enc: R2-validated kernel, verbatim ----------------
__global__ __launch_bounds__(256, 2) void enc_kernel(
    const float* __restrict__ seq, const float* __restrict__ resp,
    float* __restrict__ wsStates) {
  __shared__ float sRe[PADDED], sIm[PADDED];
  __shared__ float4 qtab[12];
  __shared__ float utab[36][8];

  const int tid = threadIdx.x;
  const int blk = blockIdx.x;          // state index s
  const float x = seq[blk];

  buildQtab(qtab, tid, x);
  buildUtab(utab, tid, resp);
  __syncthreads();

  initProduct(sRe, sIm, tid, qtab);
  __syncthreads();

  encPass<0>(sRe, sIm, tid, 1, &utab[0], 0);
  encPass<1>(sRe, sIm, tid, 0, &utab[4], 0);
  encPass<2>(sRe, sIm, tid, 0, &utab[8], 0x555);
  encPass<0>(sRe, sIm, tid, 2, &utab[12], 0);
  encPass<1>(sRe, sIm, tid, 0, &utab[16], 0);
  encPass<2>(sRe, sIm, tid, 0, &utab[20], 0x2AA);
  encPass<0>(sRe, sIm, tid, 2, &utab[24], 0);
  encPass<1>(sRe, sIm, tid, 0, &utab[28], 0);

  // final pass: gates 8-11 (layout2) + CZ(0x555), store with CX_LONG fold
  {
    float ar[16], ai[16];
    ldsRead16<2>(sRe, sIm, tid, 0, ar, ai);
    applyU34(ar, ai, &utab[32]);
    float* gR = wsStates + (size_t)blk * 8192;
    float* gI = gR + 4096;
#pragma unroll
    for (int r = 0; r < 16; ++r) {
      int j = (r << 8) | tid;
      float sg = (__popc((j & (j >> 1)) & 0x555) & 1) ? -1.0f : 1.0f;
      int g = j ^ ((j & 1) << 11);  // involution
      gR[g] = sg * ar[r];
      gI[g] = sg * ai[r];
    }
  }
}

// ---------------- proj: single-LDS-plane re-sequencing of R2 passes ----------------
// perm: state regs stay resident; one 16.9KB plane permutes im then re.
template <int W, int R>
__device__ __forceinline__ void perm16(float* M, int tid, int map,
                                       float (&ar)[16], float (&ai)[16]) {
#pragma unroll
  for (int r = 0; r < 16; ++r) M[PD(layoutIdx<W>(tid, r))] = ai[r];
  __syncthreads();
#pragma unroll
  for (int r = 0; r < 16; ++r) ai[r] = M[PD(mapIdx(layoutIdx<R>(tid, r), map))];
  __syncthreads();
#pragma unroll
  for (int r = 0; r < 16; ++r) M[PD(layoutIdx<W>(tid, r))] = ar[r];
  __syncthreads();
#pragma unroll
  for (int r = 0; r < 16; ++r) ar[r] = M[PD(mapIdx(layoutIdx<R>(tid, r), map))];
  __syncthreads();
}

__global__ __launch_bounds__(256, 4) void proj_kernel(
    const float* __restrict__ wsStates, const float* __restrict__ ptabG,
    float* __restrict__ featBase) {
  __shared__ float M[PADDED];
  __shared__ float4 ptab[24];
  __shared__ float red[4][12];

  const int tid = threadIdx.x;
  const int bid = blockIdx.x;
  int h, which, s;
  if (bid < 2048) { s = bid >> 2; int pp = bid & 3; h = pp >> 1; which = 1 + (pp & 1); }
  else            { int i = bid - 2048; h = i & 1; s = (((i >> 1) << 6) | 63); which = 0; }
  const int b = s >> 6, t = s & 63;

  if (tid < 24) ptab[tid] = ((const float4*)ptabG)[(h * 3 + which) * 24 + tid];

  // coalesced state load: thread owns j = 16*tid .. 16*tid+15 (layout 0)
  float ar[16], ai[16];
  const float4* pR = (const float4*)(wsStates + (size_t)s * 8192 + (tid << 4));
  const float4* pI = (const float4*)(wsStates + (size_t)s * 8192 + 4096 + (tid << 4));
#pragma unroll
  for (int k = 0; k < 4; ++k) {
    float4 vr = pR[k], vi = pI[k];
    ar[4 * k] = vr.x; ar[4 * k + 1] = vr.y; ar[4 * k + 2] = vr.z; ar[4 * k + 3] = vr.w;
    ai[4 * k] = vi.x; ai[4 * k + 1] = vi.y; ai[4 * k + 2] = vi.z; ai[4 * k + 3] = vi.w;
  }
  __syncthreads();  // ptab ready

  applyRyRz4(ar, ai, &ptab[0]);          // L0 q0-3   (layout 0)
  perm16<0, 1>(M, tid, 0, ar, ai);
  applyRyRz4(ar, ai, &ptab[4]);          // L0 q4-7   (layout 1)
  perm16<1, 2>(M, tid, 0, ar, ai);
  applyRyRz4(ar, ai, &ptab[8]);          // L0 q8-11  (layout 2)
  perm16<2, 0>(M, tid, 3, ar, ai);       // ladder fold (R2-validated mode 3)
  applyRyRz4(ar, ai, &ptab[12]);         // L1 q0-3   (layout 0)
  perm16<0, 1>(M, tid, 0, ar, ai);
  applyRyRz4(ar, ai, &ptab[16]);         // L1 q4-7   (layout 1)
  perm16<1, 2>(M, tid, 0, ar, ai);
  applyRyRz4(ar, ai, &ptab[20]);         // L1 q8-11  (layout 2)

  // features (R2 projFinal sign math, verbatim; regs are layout 2)
  float sp = 0.f, f0 = 0.f, f1 = 0.f, f2 = 0.f, f3 = 0.f;
  int pt = __popc(tid) & 1;
#pragma unroll
  for (int r = 0; r < 16; ++r) {
    float p = ar[r] * ar[r] + ai[r] * ai[r];
    sp += p;
    int tr = r ^ (r << 1); tr ^= (tr << 2);  // 4-bit prefix-xor of r
    f0 += ((pt ^ ((tr >> 3) & 1)) ? -p : p);
    f1 += ((pt ^ ((tr >> 2) & 1)) ? -p : p);
    f2 += ((pt ^ ((tr >> 1) & 1)) ? -p : p);
    f3 += ((pt ^ (tr & 1)) ? -p : p);
  }
  float feat[12];
  feat[0] = f0; feat[1] = f1; feat[2] = f2; feat[3] = f3;
  int tt = tid ^ (tid << 1); tt ^= (tt << 2); tt ^= (tt << 4);  // 8-bit prefix-xor
#pragma unroll
  for (int q = 4; q < 12; ++q)
    feat[q] = ((tt >> (11 - q)) & 1) ? -sp : sp;

#pragma unroll
  for (int q = 0; q < 12; ++q) feat[q] = waveReduce(feat[q]);
  int wid = tid >> 6;
  if ((tid & 63) == 0) {
#pragma unroll
    for (int q = 0; q < 12; ++q) red[wid][q] = feat[q];
  }
  __syncthreads();
  if (tid < 12) {
    float v = red[0][tid] + red[1][tid] + red[2][tid] + red[3][tid];
    float* dst;
    if (which == 1)      dst = featBase + (((h << 3) + b) * 64 + t) * 12;
    else if (which == 2) dst = featBase + 12288 + (((h << 3) + b) * 64 + t) * 12;
    else                 dst = featBase + 24576 + ((h << 3) + b) * 12;
    dst[tid] = v;
  }
}

// ================= MONO FALLBACK (R1-validated) =================
template <int L>
__device__ __forceinline__ void projPassM(float* sR, float* sI, int tid, int mode, const float4* gt) {
  float ar[16], ai[16];
  ldsRead16<L>(sR, sI, tid, mode, ar, ai);
  if (mode != 0) __syncthreads();
  applyRyRz4(ar, ai, gt);
  ldsWrite16<L>(sR, sI, tid, ar, ai, 0);
  __syncthreads();
}
__device__ __forceinline__ void projFinalM(const float* sR, const float* sI, int tid,
                                           const float4* gt, float feat[12]) {
  float ar[16], ai[16];
#pragma unroll
  for (int r = 0; r < 16; ++r) {
    int a = PD((r << 8) | tid);
    ar[r] = sR[a]; ai[r] = sI[a];
  }
  applyRyRz4(ar, ai, gt);
  float sp = 0.f, f0 = 0.f, f1 = 0.f, f2 = 0.f, f3 = 0.f;
  int pt = __popc(tid) & 1;
#pragma unroll
  for (int r = 0; r < 16; ++r) {
    float p = ar[r] * ar[r] + ai[r] * ai[r];
    sp += p;
    int tr = r ^ (r << 1); tr ^= (tr << 2);
    f0 += ((pt ^ ((tr >> 3) & 1)) ? -p : p);
    f1 += ((pt ^ ((tr >> 2) & 1)) ? -p : p);
    f2 += ((pt ^ ((tr >> 1) & 1)) ? -p : p);
    f3 += ((pt ^ (tr & 1)) ? -p : p);
  }
  feat[0] = f0; feat[1] = f1; feat[2] = f2; feat[3] = f3;
  int tt = tid ^ (tid << 1); tt ^= (tt << 2); tt ^= (tt << 4);
#pragma unroll
  for (int q = 4; q < 12; ++q)
    feat[q] = ((tt >> (11 - q)) & 1) ? -sp : sp;
}
__global__ __launch_bounds__(256, 2) void qstates_mono(
    const float* __restrict__ seq, const float* __restrict__ resp,
    const float* __restrict__ hparams, float* __restrict__ featBase) {
  __shared__ float sRe[PADDED], sIm[PADDED];
  __shared__ float4 qtab[12];
  __shared__ float utab[36][8];
  __shared__ float4 ptab[24];
  __shared__ float red[4][12];
  const int tid = threadIdx.x;
  const int blk = blockIdx.x;
  const int b = blk >> 6, t = blk & 63;
  const float x = seq[blk];
  buildQtab(qtab, tid, x);
  buildUtab(utab, tid, resp);
  __syncthreads();
  initProduct(sRe, sIm, tid, qtab);
  __syncthreads();
  for (int ly = 0; ly < 3; ++ly) {
    int czm = (ly & 1) ? 0x2AA : 0x555;
    encPass<0>(sRe, sIm, tid, (ly == 0) ? 1 : 2, &utab[ly * 12], 0);
    encPass<1>(sRe, sIm, tid, 0, &utab[ly * 12 + 4], 0);
    encPass<2>(sRe, sIm, tid, 0, &utab[ly * 12 + 8], czm);
  }
  float encR[16], encI[16];
#pragma unroll
  for (int r = 0; r < 16; ++r) {
    int j = (tid << 4) | r;
    int a = PD(j ^ ((j & 1) << 11));
    encR[r] = sRe[a]; encI[r] = sIm[a];
  }
  const int nproj = (t == 63) ? 6 : 4;
  for (int pj = 0; pj < nproj; ++pj) {
    int h, which;
    if (pj < 4) { h = pj >> 1; which = (pj & 1) ? 2 : 1; }
    else        { h = pj - 4;  which = 0; }
    buildPtab(ptab, tid, hparams + (h * 3 + which) * 48);
    __syncthreads();
    float ar[16], ai[16];
#pragma unroll
    for (int r = 0; r < 16; ++r) { ar[r] = encR[r]; ai[r] = encI[r]; }
    applyRyRz4(ar, ai, &ptab[0]);
    ldsWrite16<0>(sRe, sIm, tid, ar, ai, 0);
    __syncthreads();
    projPassM<1>(sRe, sIm, tid, 0, &ptab[4]);
    projPassM<2>(sRe, sIm, tid, 0, &ptab[8]);
    projPassM<0>(sRe, sIm, tid, 3, &ptab[12]);
    projPassM<1>(sRe, sIm, tid, 0, &ptab[16]);
    float feat[12];
    projFinalM(sRe, sIm, tid, &ptab[20], feat);
#pragma unroll
    for (int q = 0; q < 12; ++q) feat[q] = waveReduce(feat[q]);
    int wid = tid >> 6;
    if ((tid & 63) == 0) {
#pragma unroll
      for (int q = 0; q < 12; ++q) red[wid][q] = feat[q];
    }
    __syncthreads();
    if (tid < 12) {
      float v = red[0][tid] + red[1][tid] + red[2][tid] + red[3][tid];
      float* dst;
      if (which == 1)      dst = featBase + (((h << 3) + b) * 64 + t) * 12;
      else if (which == 2) dst = featBase + 12288 + (((h << 3) + b) * 64 + t) * 12;
      else                 dst = featBase + 24576 + ((h << 3) + b) * 12;
      dst[tid] = v;
    }
    __syncthreads();
  }
}

// ================= HEAD =================
__global__ __launch_bounds__(64) void qhead_kernel(
    const float* __restrict__ featBase,
    const float* __restrict__ W1, const float* __restrict__ b1,
    const float* __restrict__ W2, const float* __restrict__ b2,
    float* __restrict__ out) {
  __shared__ float feats[24];
  __shared__ float hdn[48];
  const int b = blockIdx.x;
  const int lane = threadIdx.x;
  const float* Kf = featBase;
  const float* Vf = featBase + 12288;
  const float* Qf = featBase + 24576;
  for (int h = 0; h < 2; ++h) {
    const float* q  = Qf + ((h << 3) + b) * 12;
    const float* kr = Kf + ((((h << 3) + b) << 6) + lane) * 12;
    float dot = 0.f;
#pragma unroll
    for (int d = 0; d < 12; ++d) dot += q[d] * kr[d];
    dot *= 0.288675134594812882f;  // 1/sqrt(12); mask row 63 all-zero
    float mx = dot;
#pragma unroll
    for (int off = 32; off; off >>= 1) mx = fmaxf(mx, __shfl_xor(mx, off, 64));
    float e = expf(dot - mx);
    float se = e;
#pragma unroll
    for (int off = 32; off; off >>= 1) se += __shfl_xor(se, off, 64);
    float a = e / se;
    const float* vr = Vf + ((((h << 3) + b) << 6) + lane) * 12;
#pragma unroll
    for (int d = 0; d < 12; ++d) {
      float v = a * vr[d];
#pragma unroll
      for (int off = 32; off; off >>= 1) v += __shfl_xor(v, off, 64);
      if (lane == 0) feats[h * 12 + d] = v;
    }
  }
  __syncthreads();
  if (lane < 48) {
    float acc = b1[lane];
#pragma unroll
    for (int f = 0; f < 24; ++f) acc += feats[f] * W1[f * 48 + lane];
    hdn[lane] = 0.5f * acc * (1.0f + erff(acc * 0.70710678118654752440f));
  }
  __syncthreads();
  if (lane < 4) {
    float acc = b2[lane];
#pragma unroll
    for (int k = 0; k < 48; ++k) acc += hdn[k] * W2[k * 4 + lane];
    out[(b << 2) | lane] = acc;
  }
}

extern "C" void kernel_launch(void* const* d_in, const int* in_sizes, int n_in,
                              void* d_out, int out_size, void* d_ws, size_t ws_size,
                              hipStream_t stream) {
  const float* seq     = (const float*)d_in[0];
  const float* resp    = (const float*)d_in[1];
  const float* hparams = (const float*)d_in[2];
  const float* W1      = (const float*)d_in[3];
  const float* b1      = (const float*)d_in[4];
  const float* W2      = (const float*)d_in[5];
  const float* b2      = (const float*)d_in[6];
  float* out = (float*)d_out;
  float* ws  = (float*)d_ws;

  const size_t needSplit = (size_t)WS_TOTAL * sizeof(float);
  if (ws_size >= needSplit) {
    float* wsStates = ws;
    float* featBase = ws + WS_FEAT;
    float* ptabG    = ws + WS_PTAB;
    hipLaunchKernelGGL(prep_kernel, dim3(1), dim3(256), 0, stream, hparams, ws);
    hipLaunchKernelGGL(enc_kernel, dim3(512), dim3(256), 0, stream, seq, resp, wsStates);
    hipLaunchKernelGGL(proj_kernel, dim3(2064), dim3(256), 0, stream, wsStates, ptabG, featBase);
    hipLaunchKernelGGL(qhead_kernel, dim3(8), dim3(64), 0, stream, featBase, W1, b1, W2, b2, out);
  } else {
    hipLaunchKernelGGL(qstates_mono, dim3(512), dim3(256), 0, stream, seq, resp, hparams, ws);
    hipLaunchKernelGGL(qhead_kernel, dim3(8), dim3(64), 0, stream, ws, W1, b1, W2, b2, out);
  }
}